// Round 1
// baseline (229.491 us; speedup 1.0000x reference)
//
#include <hip/hip_runtime.h>

#define IMG_H 1024
#define IMG_W 1024
#define TX 64
#define TY 16
#define HALO 2
#define INW (TX + 2*HALO)   // 68
#define INH (TY + 2*HALO)   // 20
#define FW (TX + 2)         // 66
#define FH (TY + 2)         // 18

// One Perona-Malik iteration, fused: Sobel grads -> conduction -> flux ->
// Sobel divergence -> Euler update. 5x5 input stencil per output pixel.
__global__ __launch_bounds__(256) void pm_iter(const float* __restrict__ in,
                                               float* __restrict__ out) {
    __shared__ float sIn[INH][INW];
    __shared__ float sFx[FH][FW];
    __shared__ float sFy[FH][FW];

    const int tx0 = blockIdx.x * TX;
    const int ty0 = blockIdx.y * TY;
    const int n   = blockIdx.z;
    const float* img = in + (size_t)n * IMG_H * IMG_W;
    float* o         = out + (size_t)n * IMG_H * IMG_W;
    const int tid = threadIdx.x;

    // ---- Stage input tile with halo=2; zero outside the image (SAME pad) ----
    for (int i = tid; i < INH * INW; i += 256) {
        const int r = i / INW, c = i % INW;
        const int gy = ty0 + r - HALO, gx = tx0 + c - HALO;
        float v = 0.f;
        if (gy >= 0 && gy < IMG_H && gx >= 0 && gx < IMG_W) v = img[gy * IMG_W + gx];
        sIn[r][c] = v;
    }
    __syncthreads();

    const float inv8  = 0.125f;
    const float invK2 = 1.0f / (0.05f * 0.05f);   // 1/kappa^2 = 400

    // ---- Flux on (TY+2)x(TX+2); flux is ZERO outside the image (the second
    //      conv zero-pads the flux array, not flux-of-padding). ----
    for (int i = tid; i < FH * FW; i += 256) {
        const int r = i / FW, c = i % FW;          // flux coords
        const int gy = ty0 + r - 1, gx = tx0 + c - 1;
        float fx = 0.f, fy = 0.f;
        if (gy >= 0 && gy < IMG_H && gx >= 0 && gx < IMG_W) {
            const int rr = r + 1, cc = c + 1;      // center in sIn coords
            const float a00 = sIn[rr-1][cc-1], a01 = sIn[rr-1][cc], a02 = sIn[rr-1][cc+1];
            const float a10 = sIn[rr  ][cc-1],                      a12 = sIn[rr  ][cc+1];
            const float a20 = sIn[rr+1][cc-1], a21 = sIn[rr+1][cc], a22 = sIn[rr+1][cc+1];
            // cross-correlation with sx, sy (XLA convs don't flip kernels)
            const float gxv = (a02 - a00 + 2.f*(a12 - a10) + (a22 - a20)) * inv8;
            const float gyv = (a20 - a00 + 2.f*(a21 - a01) + (a22 - a02)) * inv8;
            // c = 1/(1 + (sqrt(s)/k)^2) == 1/(1 + s/k^2)
            const float s = gxv*gxv + gyv*gyv + 1e-8f;
            const float cond = 1.f / (1.f + s * invK2);
            fx = cond * gxv;
            fy = cond * gyv;
        }
        sFx[r][c] = fx;
        sFy[r][c] = fy;
    }
    __syncthreads();

    // ---- Divergence + Euler update on the TX x TY core ----
    const int lx  = tid & 63;   // column within tile
    const int ly0 = tid >> 6;   // 0..3
    #pragma unroll
    for (int k = 0; k < 4; ++k) {
        const int ly = ly0 * 4 + k;            // 0..15
        const int r = ly + 1, c = lx + 1;      // center in flux coords
        const float dx = ( (sFx[r-1][c+1] - sFx[r-1][c-1])
                         + 2.f*(sFx[r][c+1] - sFx[r][c-1])
                         + (sFx[r+1][c+1] - sFx[r+1][c-1]) ) * inv8;
        const float dy = ( (sFy[r+1][c-1] - sFy[r-1][c-1])
                         + 2.f*(sFy[r+1][c] - sFy[r-1][c])
                         + (sFy[r+1][c+1] - sFy[r-1][c+1]) ) * inv8;
        const float div = dx + dy;
        const int gy = ty0 + ly, gx = tx0 + lx;
        o[gy * IMG_W + gx] = sIn[ly + HALO][lx + HALO] + 0.25f * div;
    }
}

extern "C" void kernel_launch(void* const* d_in, const int* in_sizes, int n_in,
                              void* d_out, int out_size, void* d_ws, size_t ws_size,
                              hipStream_t stream) {
    const float* img = (const float*)d_in[0];
    float* out = (float*)d_out;
    float* ws  = (float*)d_ws;            // needs >= 64 MB scratch
    const int N = in_sizes[0] / (IMG_H * IMG_W);

    dim3 grid(IMG_W / TX, IMG_H / TY, N);
    dim3 block(256);
    // ping-pong: in -> out -> ws -> out  (only one scratch buffer needed)
    pm_iter<<<grid, block, 0, stream>>>(img, out);
    pm_iter<<<grid, block, 0, stream>>>(out, ws);
    pm_iter<<<grid, block, 0, stream>>>(ws, out);
}

// Round 2
// 174.196 us; speedup vs baseline: 1.3174x; 1.3174x over previous
//
#include <hip/hip_runtime.h>

#define IMG 1024
#define BH 16            // output rows per band; 64 bands x 16 imgs = 1024 wgs = 4/CU exactly
#define ROWW 1032        // [0..4) zero pad | [4..1028) data | [1028..1032) zero pad
#define PAD 4

// Row-sweep Perona-Malik iteration. Thread t owns cols 4t..4t+3 of the band.
// Ring-of-3 LDS rows for input and flux; center values ride register pipelines,
// only halo columns (c0-1, c0+4) are read back from LDS.
__global__ __launch_bounds__(256, 4) void pm_sweep(const float* __restrict__ in,
                                                   float* __restrict__ out) {
    __shared__ __align__(16) float lds[9 * ROWW];
    float* const sIN = lds;               // rows: input ring (3)
    float* const sFX = lds + 3 * ROWW;    // flux-x ring (3)
    float* const sFY = lds + 6 * ROWW;    // flux-y ring (3)

    const int tid = threadIdx.x;
    const int y0  = blockIdx.x * BH;
    const size_t base = (size_t)blockIdx.y * IMG * IMG;
    const float* I = in + base;
    float*       O = out + base;
    const int c0 = tid << 2;
    const int di = PAD + c0;

    // register pipelines (input rows and flux rows)
    float r0[4] = {0,0,0,0}, r1[4] = {0,0,0,0}, r2[4] = {0,0,0,0};
    float fx1[4] = {0,0,0,0}, fx2[4] = {0,0,0,0};
    float fy1[4] = {0,0,0,0}, fy2[4] = {0,0,0,0};
    float4 Lp;

    // prologue: issue load of row y0-2 (committed at k=0)
    {
        const int row = y0 - 2;
        if (row >= 0) Lp = *(const float4*)(I + ((size_t)row << 10) + c0);
        else          Lp = make_float4(0.f, 0.f, 0.f, 0.f);
    }
    // zero the never-written pad columns of all 9 LDS rows
    if (tid < 72) {
        const int r = tid >> 3, j = tid & 7;
        lds[r * ROWW + ((j < 4) ? j : (1024 + j))] = 0.f;
    }
    __syncthreads();

    int slI = 0;                      // input-ring slot for row yld = (k % 3)
    for (int k = 0; k < BH + 4; ++k) {
        const int yld = y0 - 2 + k;

        // ---- commit pending load: LDS + register pipeline ----
        *(float4*)(sIN + slI * ROWW + di) = Lp;
        #pragma unroll
        for (int j = 0; j < 4; ++j) { r2[j] = r1[j]; r1[j] = r0[j]; }
        r0[0] = Lp.x; r0[1] = Lp.y; r0[2] = Lp.z; r0[3] = Lp.w;

        // ---- issue next row's load (one-step lookahead) ----
        if (k <= BH + 2) {
            const int row = yld + 1;
            if (row >= 0 && row < IMG)
                Lp = *(const float4*)(I + ((size_t)row << 10) + c0);
            else
                Lp = make_float4(0.f, 0.f, 0.f, 0.f);
        }
        __syncthreads();   // bar1: IN row visible; prev-step div reads done

        const int sl1 = (slI == 2) ? 0 : slI + 1;   // (slI+1)%3
        const int sl2 = (sl1 == 2) ? 0 : sl1 + 1;   // (slI+2)%3

        // ---- flux row yf = yld-1 (rows yf-1,yf,yf+1 = r2,r1,r0 / slots sl1,sl2,slI) ----
        float fxN[4], fyN[4];
        if (k >= 2) {
            const int yf = yld - 1;
            if (yf >= 0 && yf < IMG) {
                float um[6], uc[6], up[6];
                um[0] = sIN[sl1*ROWW + di - 1]; um[5] = sIN[sl1*ROWW + di + 4];
                uc[0] = sIN[sl2*ROWW + di - 1]; uc[5] = sIN[sl2*ROWW + di + 4];
                up[0] = sIN[slI*ROWW + di - 1]; up[5] = sIN[slI*ROWW + di + 4];
                #pragma unroll
                for (int j = 0; j < 4; ++j) { um[j+1] = r2[j]; uc[j+1] = r1[j]; up[j+1] = r0[j]; }
                float s[6], d[6];
                #pragma unroll
                for (int j = 0; j < 6; ++j) {
                    s[j] = fmaf(2.f, uc[j], um[j] + up[j]);   // col-sum (x8 scale)
                    d[j] = up[j] - um[j];                     // row-diff
                }
                #pragma unroll
                for (int i = 0; i < 4; ++i) {
                    const float GX = s[i+2] - s[i];                       // 8*grad_x
                    const float GY = fmaf(2.f, d[i+1], d[i] + d[i+2]);    // 8*grad_y
                    const float m2 = fmaf(GY, GY, GX * GX);
                    const float mag = fmaf(m2, 0.015625f, 1e-8f);         // gx^2+gy^2+eps
                    const float den = fmaf(mag, 400.f, 1.f);              // 1+(mag/k^2)
                    const float c = __builtin_amdgcn_rcpf(den);
                    fxN[i] = c * GX;                                      // 8*flux_x
                    fyN[i] = c * GY;                                      // 8*flux_y
                }
            } else {
                #pragma unroll
                for (int i = 0; i < 4; ++i) { fxN[i] = 0.f; fyN[i] = 0.f; }
            }
            *(float4*)(sFX + sl2*ROWW + di) = make_float4(fxN[0], fxN[1], fxN[2], fxN[3]);
            *(float4*)(sFY + sl2*ROWW + di) = make_float4(fyN[0], fyN[1], fyN[2], fyN[3]);
        }
        __syncthreads();   // bar2: flux rows visible

        // ---- divergence + update, row yd = yld-2 (flux rows in slI,sl1,sl2 / regs fx2,fx1,fxN) ----
        if (k >= 4) {
            const int yd = yld - 2;
            float xm[6], xc[6], xp[6], ym[6], yp[6];
            xm[0] = sFX[slI*ROWW + di - 1]; xm[5] = sFX[slI*ROWW + di + 4];
            xc[0] = sFX[sl1*ROWW + di - 1]; xc[5] = sFX[sl1*ROWW + di + 4];
            xp[0] = sFX[sl2*ROWW + di - 1]; xp[5] = sFX[sl2*ROWW + di + 4];
            ym[0] = sFY[slI*ROWW + di - 1]; ym[5] = sFY[slI*ROWW + di + 4];
            yp[0] = sFY[sl2*ROWW + di - 1]; yp[5] = sFY[sl2*ROWW + di + 4];
            #pragma unroll
            for (int j = 0; j < 4; ++j) {
                xm[j+1] = fx2[j]; xc[j+1] = fx1[j]; xp[j+1] = fxN[j];
                ym[j+1] = fy2[j];                   yp[j+1] = fyN[j];
            }
            float S2[6], D2[6];
            #pragma unroll
            for (int j = 0; j < 6; ++j) {
                S2[j] = fmaf(2.f, xc[j], xm[j] + xp[j]);
                D2[j] = yp[j] - ym[j];
            }
            float o[4];
            #pragma unroll
            for (int i = 0; i < 4; ++i) {
                const float DX = S2[i+2] - S2[i];
                const float DY = fmaf(2.f, D2[i+1], D2[i] + D2[i+2]);
                o[i] = fmaf(DX + DY, 0.00390625f, r2[i]);   // in + 0.25*div (scales folded)
            }
            *(float4*)(O + ((size_t)yd << 10) + c0) = make_float4(o[0], o[1], o[2], o[3]);
        }

        // shift flux pipeline (after div consumed fx2/fy2)
        if (k >= 2) {
            #pragma unroll
            for (int j = 0; j < 4; ++j) {
                fx2[j] = fx1[j]; fx1[j] = fxN[j];
                fy2[j] = fy1[j]; fy1[j] = fyN[j];
            }
        }
        slI = (slI == 2) ? 0 : slI + 1;
    }
}

extern "C" void kernel_launch(void* const* d_in, const int* in_sizes, int n_in,
                              void* d_out, int out_size, void* d_ws, size_t ws_size,
                              hipStream_t stream) {
    const float* img = (const float*)d_in[0];
    float* out = (float*)d_out;
    float* ws  = (float*)d_ws;
    const int N = in_sizes[0] / (IMG * IMG);

    dim3 grid(IMG / BH, N);
    dim3 block(256);
    pm_sweep<<<grid, block, 0, stream>>>(img, out);
    pm_sweep<<<grid, block, 0, stream>>>(out, ws);
    pm_sweep<<<grid, block, 0, stream>>>(ws, out);
}

// Round 4
// 165.812 us; speedup vs baseline: 1.3840x; 1.0506x over previous
//
#include <hip/hip_runtime.h>

#define IMG 1024
#define BH  16   // output rows per wave-band; 64 bands x 16 images x 4 col-strips

// Barrier-free, LDS-free Perona-Malik iteration.
// Each lane owns 4 output cols (c0..c0+3) and redundantly computes a 6-wide
// flux window (c0-1..c0+4) from an 8-wide input window (c0-2..c0+5), so the
// divergence stencil needs no cross-lane exchange at all. Vertical neighbors
// ride register ring-buffers; rows are swept with a 1-row load lookahead.
__global__ __launch_bounds__(256, 4)
void pm_sweep(const float* __restrict__ in, float* __restrict__ out) {
    const int tid = threadIdx.x;
    const int c0  = tid << 2;                       // 0..1020
    const int y0  = blockIdx.x * BH;
    const size_t base = (size_t)blockIdx.y << 20;   // * IMG*IMG
    const float* I = in + base;
    float*       O = out + base;

    const bool le = (c0 == 0);          // image left edge lane
    const bool re = (c0 == IMG - 4);    // image right edge lane
    const int aC = le ? 0 : c0 - 2;     // 8B-aligned, in-bounds
    const int bC = re ? IMG - 4 : c0 + 2;

    // register pipelines: input rows (8 wide), flux rows (6 wide x 2 comps)
    float r0[8], r1[8], r2[8];
    float f1x[6], f1y[6], f2x[6], f2y[6];
    #pragma unroll
    for (int j = 0; j < 8; ++j) { r0[j] = 0.f; r1[j] = 0.f; r2[j] = 0.f; }
    #pragma unroll
    for (int j = 0; j < 6; ++j) { f1x[j] = 0.f; f1y[j] = 0.f; f2x[j] = 0.f; f2y[j] = 0.f; }

    float4 A = make_float4(0.f, 0.f, 0.f, 0.f), B = A;
    if (y0 >= 2) {  // prologue: row y0-2
        const size_t r = (size_t)(y0 - 2) << 10;
        A = *(const float4*)(I + r + aC);
        B = *(const float4*)(I + r + bC);
    }

    #pragma unroll
    for (int k = 0; k < BH + 4; ++k) {
        const int yld = y0 - 2 + k;

        // ---- commit pending load into the input ring (8-wide window) ----
        #pragma unroll
        for (int j = 0; j < 8; ++j) { r2[j] = r1[j]; r1[j] = r0[j]; }
        r0[0] = le ? 0.f : A.x;  r0[1] = le ? 0.f : A.y;
        r0[2] = le ? A.x : A.z;  r0[3] = le ? A.y : A.w;
        r0[4] = re ? B.z : B.x;  r0[5] = re ? B.w : B.y;
        r0[6] = re ? 0.f : B.z;  r0[7] = re ? 0.f : B.w;

        // ---- issue next row's load (wave-uniform branch) ----
        if (k < BH + 3) {
            const int row = yld + 1;
            if (row >= 0 && row < IMG) {
                const size_t r = (size_t)row << 10;
                A = *(const float4*)(I + r + aC);
                B = *(const float4*)(I + r + bC);
            } else { A = make_float4(0.f, 0.f, 0.f, 0.f); B = A; }
        }

        // ---- flux row yf = yld-1 on 6-wide window (cols c0-1..c0+4) ----
        float fNx[6], fNy[6];
        const int yf = yld - 1;
        if (yf >= 0 && yf < IMG) {
            float s[8], d[8];
            #pragma unroll
            for (int j = 0; j < 8; ++j) {
                s[j] = fmaf(2.f, r1[j], r2[j] + r0[j]);   // col sums   (x8 scale)
                d[j] = r0[j] - r2[j];                     // row diffs
            }
            #pragma unroll
            for (int i = 0; i < 6; ++i) {
                const float GX  = s[i+2] - s[i];                     // 8*grad_x
                const float GY  = fmaf(2.f, d[i+1], d[i] + d[i+2]);  // 8*grad_y
                const float m2  = fmaf(GY, GY, GX * GX);
                const float mag = fmaf(m2, 0.015625f, 1e-8f);        // gx^2+gy^2+eps
                const float den = fmaf(mag, 400.f, 1.f);             // 1 + mag/kappa^2
                const float c   = __builtin_amdgcn_rcpf(den);
                fNx[i] = c * GX;                                     // 8*flux_x
                fNy[i] = c * GY;                                     // 8*flux_y
            }
            // flux is zero-padded by the second conv: kill cols -1 / 1024
            if (le) { fNx[0] = 0.f; fNy[0] = 0.f; }
            if (re) { fNx[5] = 0.f; fNy[5] = 0.f; }
        } else {
            #pragma unroll
            for (int i = 0; i < 6; ++i) { fNx[i] = 0.f; fNy[i] = 0.f; }
        }

        // ---- divergence + Euler update, row yd = yld-2 (f2,f1,fN = yd-1,yd,yd+1) ----
        if (k >= 4) {
            float S[6], D[6];
            #pragma unroll
            for (int j = 0; j < 6; ++j) {
                S[j] = fmaf(2.f, f1x[j], f2x[j] + fNx[j]);
                D[j] = fNy[j] - f2y[j];
            }
            float o[4];
            #pragma unroll
            for (int i = 0; i < 4; ++i) {
                const float DX = S[i+2] - S[i];
                const float DY = fmaf(2.f, D[i+1], D[i] + D[i+2]);
                o[i] = fmaf(DX + DY, 0.00390625f, r2[i+2]);   // in + 0.25*div/64
            }
            const int yd = yld - 2;
            *(float4*)(O + ((size_t)yd << 10) + c0) = make_float4(o[0], o[1], o[2], o[3]);
        }

        // ---- shift flux ring ----
        #pragma unroll
        for (int j = 0; j < 6; ++j) {
            f2x[j] = f1x[j]; f2y[j] = f1y[j];
            f1x[j] = fNx[j]; f1y[j] = fNy[j];
        }
    }
}

extern "C" void kernel_launch(void* const* d_in, const int* in_sizes, int n_in,
                              void* d_out, int out_size, void* d_ws, size_t ws_size,
                              hipStream_t stream) {
    const float* img = (const float*)d_in[0];
    float* out = (float*)d_out;
    float* ws  = (float*)d_ws;
    const int N = in_sizes[0] / (IMG * IMG);

    dim3 grid(IMG / BH, N);
    dim3 block(256);
    pm_sweep<<<grid, block, 0, stream>>>(img, out);
    pm_sweep<<<grid, block, 0, stream>>>(out, ws);
    pm_sweep<<<grid, block, 0, stream>>>(ws, out);
}